// Round 6
// baseline (1587.173 us; speedup 1.0000x reference)
//
#include <hip/hip_runtime.h>
#include <stdint.h>

// LTC encoder B=256,T=1024,F=64,H=128, f32. One WG per batch row.
// Wave-specialized pipeline: waves 0-3 (A) = layer 0 at step t,
// waves 4-7 (B) = layer 1 at step t-1. 2 barriers per pipelined step.
// K-split 4 within a quad of lanes (DPP combine); 2 outputs per thread.
// R4 lesson: weight arrays (float wh[64]...) were NOT register-resident
// (VGPR_Count=116 despite waves_per_eu(2,2)) -> re-fetched per iter, L2-bound.
// R6: weights in NAMED float4 vars, pinned via asm -> allocator must keep them.
// (R5 = this same idea, killed by a macro-parameter/member-name collision.)

#define B_ 256
#define T_ 1024
#define F_ 64
#define H_ 128
#define EPS_ 1e-5f
#define NT_ 512

__device__ __forceinline__ float tanh_fast(float a) {
  float aa = fabsf(a);
  float e  = __expf(2.f * aa);
  float th = 1.f - 2.f / (e + 1.f);
  return copysignf(th, a);
}
__device__ __forceinline__ float softplus_fast(float x) {
  return (x > 20.f) ? x : __logf(1.f + __expf(x));
}
// swizzle: +8 words per 32-word quarter -> quarter q starts at bank 8q
__device__ __forceinline__ int swz(int m) { return m + ((m >> 5) << 3); }

#define PIN4(V_) asm volatile("" : "+v"((V_).x), "+v"((V_).y), "+v"((V_).z), "+v"((V_).w))
#define DECL8(P_) float4 P_##0, P_##1, P_##2, P_##3, P_##4, P_##5, P_##6, P_##7;
#define DECL4(P_) float4 P_##0, P_##1, P_##2, P_##3;
#define LOAD8(P_, SRC_) { const float4* _s = (const float4*)(SRC_); \
  P_##0=_s[0]; P_##1=_s[1]; P_##2=_s[2]; P_##3=_s[3]; P_##4=_s[4]; P_##5=_s[5]; P_##6=_s[6]; P_##7=_s[7]; }
#define LOAD4(P_, SRC_) { const float4* _s = (const float4*)(SRC_); \
  P_##0=_s[0]; P_##1=_s[1]; P_##2=_s[2]; P_##3=_s[3]; }
#define PIN8(P_) PIN4(P_##0); PIN4(P_##1); PIN4(P_##2); PIN4(P_##3); PIN4(P_##4); PIN4(P_##5); PIN4(P_##6); PIN4(P_##7);
#define PINQ(P_) PIN4(P_##0); PIN4(P_##1); PIN4(P_##2); PIN4(P_##3);

// NOTE: parameter names must not collide with .x/.y/.z/.w member tokens.
#define FMA4(ACC_, W_, HV_) \
  ACC_ = fmaf((W_).x, (HV_).x, ACC_); ACC_ = fmaf((W_).y, (HV_).y, ACC_); \
  ACC_ = fmaf((W_).z, (HV_).z, ACC_); ACC_ = fmaf((W_).w, (HV_).w, ACC_);

// one LDS float4 broadcast feeding two weight rows (pa0/pa1)
#define H2(HQP_, OFF_, WA_, WB_) { float4 hv_ = *(const float4*)((HQP_) + (OFF_)); \
  FMA4(pa0, WA_, hv_) FMA4(pa1, WB_, hv_) }
// one LDS float4 feeding four weight rows (pa0/pa1/pt0/pt1)
#define H4(HQP_, OFF_, WA_, WB_, WC_, WD_) { float4 hv_ = *(const float4*)((HQP_) + (OFF_)); \
  FMA4(pa0, WA_, hv_) FMA4(pa1, WB_, hv_) FMA4(pt0, WC_, hv_) FMA4(pt1, WD_, hv_) }

// shared tail: quad combine (DPP), cell math, LN (wave butterfly + LDS partials),
// state write. Exactly 2 __syncthreads.
__device__ __forceinline__ float ln_tail(
    float pa0, float pt0, float pa1, float pt1, float hold,
    float bhx, float btr, float taub, float gr, float ber,
    int par, int l, int wid, float2* part, int pbase,
    float* dst, int jp, bool we)
{
  pa0 += __shfl_xor(pa0, 1); pa0 += __shfl_xor(pa0, 2);
  pt0 += __shfl_xor(pt0, 1); pt0 += __shfl_xor(pt0, 2);
  pa1 += __shfl_xor(pa1, 1); pa1 += __shfl_xor(pa1, 2);
  pt1 += __shfl_xor(pt1, 1); pt1 += __shfl_xor(pt1, 2);
  float aa = par ? pa1 : pa0;       // parity split: one j' per lane
  float tt = par ? pt1 : pt0;
  float f   = tanh_fast(aa + bhx);
  float tau = taub + softplus_fast(tt + btr);
  float hc  = fmaf(f - hold, __builtin_amdgcn_rcpf(tau), hold);
  float s = hc, s2 = hc * hc;
  #pragma unroll
  for (int off = 1; off <= 32; off <<= 1) {
    s  += __shfl_xor(s, off);
    s2 += __shfl_xor(s2, off);
  }
  if (l == 0) part[wid] = make_float2(s, s2);
  __syncthreads();                                   // barrier 1
  float4 p01 = *(const float4*)(part + pbase);
  float4 p23 = *(const float4*)(part + pbase + 2);
  float mu = (p01.x + p01.z + p23.x + p23.z) * (1.f / 256.f);  // each j counted 2x
  float m2 = (p01.y + p01.w + p23.y + p23.w) * (1.f / 256.f);
  float rstd = rsqrtf(m2 - mu * mu + EPS_);
  float hn = fmaf((hc - mu) * rstd, gr, ber);
  if (we && (l & 2) == 0) dst[swz(jp)] = hn;
  __syncthreads();                                   // barrier 2
  return hn;
}

__global__ void __attribute__((amdgpu_flat_work_group_size(NT_, NT_)))
                __attribute__((amdgpu_waves_per_eu(2, 2)))
ltc_scan(
    const float* __restrict__ x,
    const float* __restrict__ Wh0, const float* __restrict__ bh0,
    const float* __restrict__ Wx0, const float* __restrict__ bx0,
    const float* __restrict__ Wt0, const float* __restrict__ bt0,
    const float* __restrict__ tau0, const float* __restrict__ g0,
    const float* __restrict__ be0,
    const float* __restrict__ Wh1, const float* __restrict__ bh1,
    const float* __restrict__ Wx1, const float* __restrict__ bx1,
    const float* __restrict__ Wt1, const float* __restrict__ bt1,
    const float* __restrict__ tau1, const float* __restrict__ g1,
    const float* __restrict__ be1,
    float* __restrict__ out)
{
  __shared__ __align__(16) float  h0buf[2][160];   // swizzled H=128
  __shared__ __align__(16) float  h1buf[160];
  __shared__ __align__(16) float2 part[8];

  const int tid = threadIdx.x;
  const int wid = tid >> 6;
  const int l   = tid & 63;
  const int gw  = wid & 3;         // wave within group
  const int q   = l & 3;           // K-quarter
  const int k   = l >> 2;          // 0..15
  const int par = l & 1;
  const int j0  = gw * 16 + k;     // outputs j0 and j0+64
  const int jp  = j0 + (par ? 64 : 0);
  const int b   = blockIdx.x;

  if (tid < 160) { h0buf[0][tid] = 0.f; h0buf[1][tid] = 0.f; h1buf[tid] = 0.f; }
  __syncthreads();

  if (wid < 4) {
    // ================= group A: layer 0, step t = i =================
    DECL8(ra) DECL8(rb) DECL4(rc) DECL4(rd) DECL4(re) DECL4(rf)
    LOAD8(ra, Wh0 + j0 * H_ + q * 32)
    LOAD8(rb, Wh0 + (j0 + 64) * H_ + q * 32)
    LOAD4(rc, Wx0 + j0 * F_ + q * 16)
    LOAD4(rd, Wx0 + (j0 + 64) * F_ + q * 16)
    LOAD4(re, Wt0 + j0 * F_ + q * 16)
    LOAD4(rf, Wt0 + (j0 + 64) * F_ + q * 16)
    PIN8(ra) PIN8(rb) PINQ(rc) PINQ(rd) PINQ(re) PINQ(rf)

    const float bhx = bh0[jp] + bx0[jp];
    const float btr = bt0[jp];
    const float taub = tau0[jp];
    const float gr = g0[jp], ber = be0[jp];

    const float4* xg = (const float4*)(x + (size_t)b * (T_ * F_));
    // distance-2 register prefetch of the thread's x quarter (16 floats)
    float4 xa0 = xg[q * 4 + 0], xa1 = xg[q * 4 + 1], xa2 = xg[q * 4 + 2], xa3 = xg[q * 4 + 3];
    float4 xb0 = xg[16 + q * 4 + 0], xb1 = xg[16 + q * 4 + 1],
           xb2 = xg[16 + q * 4 + 2], xb3 = xg[16 + q * 4 + 3];

    auto stepA = [&](int i, float4& x0, float4& x1, float4& x2, float4& x3) {
      const float* hp = h0buf[i & 1];                // h0[i-1]
      const float* hq = hp + 40 * q;
      float pa0 = 0.f, pt0 = 0.f, pa1 = 0.f, pt1 = 0.f;
      H2(hq,  0, ra0, rb0) H2(hq,  4, ra1, rb1)
      H2(hq,  8, ra2, rb2) H2(hq, 12, ra3, rb3)
      H2(hq, 16, ra4, rb4) H2(hq, 20, ra5, rb5)
      H2(hq, 24, ra6, rb6) H2(hq, 28, ra7, rb7)
      FMA4(pa0, rc0, x0) FMA4(pa0, rc1, x1) FMA4(pa0, rc2, x2) FMA4(pa0, rc3, x3)
      FMA4(pa1, rd0, x0) FMA4(pa1, rd1, x1) FMA4(pa1, rd2, x2) FMA4(pa1, rd3, x3)
      FMA4(pt0, re0, x0) FMA4(pt0, re1, x1) FMA4(pt0, re2, x2) FMA4(pt0, re3, x3)
      FMA4(pt1, rf0, x0) FMA4(pt1, rf1, x1) FMA4(pt1, rf2, x2) FMA4(pt1, rf3, x3)
      float hold = hp[swz(jp)];
      int tn = i + 2; if (tn > T_ - 1) tn = T_ - 1;   // reload this buffer for t=i+2
      const float4* xp = xg + tn * 16 + q * 4;
      x0 = xp[0]; x1 = xp[1]; x2 = xp[2]; x3 = xp[3];
      ln_tail(pa0, pt0, pa1, pt1, hold, bhx, btr, taub, gr, ber,
              par, l, wid, part, 0, h0buf[(i + 1) & 1], jp, true);
    };

    for (int i = 0; i < T_; i += 2) {
      stepA(i, xa0, xa1, xa2, xa3);
      stepA(i + 1, xb0, xb1, xb2, xb3);
    }
    stepA(T_, xa0, xa1, xa2, xa3);                   // pipeline drain (result unused)
  } else {
    // ================= group B: layer 1, step t = i-1 =================
    DECL8(sa) DECL8(sb) DECL8(sc) DECL8(sd) DECL8(se) DECL8(sf)
    LOAD8(sa, Wh1 + j0 * H_ + q * 32)
    LOAD8(sb, Wh1 + (j0 + 64) * H_ + q * 32)
    LOAD8(sc, Wx1 + j0 * H_ + q * 32)
    LOAD8(sd, Wx1 + (j0 + 64) * H_ + q * 32)
    LOAD8(se, Wt1 + j0 * H_ + q * 32)
    LOAD8(sf, Wt1 + (j0 + 64) * H_ + q * 32)
    PIN8(sa) PIN8(sb) PIN8(sc) PIN8(sd) PIN8(se) PIN8(sf)

    const float bhx = bh1[jp] + bx1[jp];
    const float btr = bt1[jp];
    const float taub = tau1[jp];
    const float gr = g1[jp], ber = be1[jp];

    float hnlast = 0.f;
    for (int i = 0; i <= T_; ++i) {
      const float* hp  = h0buf[i & 1];               // h0[i-1] (layer-0 output)
      const float* hq0 = hp + 40 * q;
      const float* hq1 = h1buf + 40 * q;             // h1[i-2]
      float pa0 = 0.f, pt0 = 0.f, pa1 = 0.f, pt1 = 0.f;
      H2(hq1,  0, sa0, sb0) H2(hq1,  4, sa1, sb1)
      H2(hq1,  8, sa2, sb2) H2(hq1, 12, sa3, sb3)
      H2(hq1, 16, sa4, sb4) H2(hq1, 20, sa5, sb5)
      H2(hq1, 24, sa6, sb6) H2(hq1, 28, sa7, sb7)
      H4(hq0,  0, sc0, sd0, se0, sf0) H4(hq0,  4, sc1, sd1, se1, sf1)
      H4(hq0,  8, sc2, sd2, se2, sf2) H4(hq0, 12, sc3, sd3, se3, sf3)
      H4(hq0, 16, sc4, sd4, se4, sf4) H4(hq0, 20, sc5, sd5, se5, sf5)
      H4(hq0, 24, sc6, sd6, se6, sf6) H4(hq0, 28, sc7, sd7, se7, sf7)
      float hold = h1buf[swz(jp)];
      float hn = ln_tail(pa0, pt0, pa1, pt1, hold, bhx, btr, taub, gr, ber,
                         par, l, wid, part, 4, h1buf, jp, i > 0);
      if (i > 0) hnlast = hn;
    }
    if ((l & 2) == 0) out[b * H_ + jp] = hnlast;     // h1[T-1]
  }
}

extern "C" void kernel_launch(void* const* d_in, const int* in_sizes, int n_in,
                              void* d_out, int out_size, void* d_ws, size_t ws_size,
                              hipStream_t stream) {
  const float* x    = (const float*)d_in[0];
  const float* Wh0  = (const float*)d_in[1];
  const float* bh0  = (const float*)d_in[2];
  const float* Wx0  = (const float*)d_in[3];
  const float* bx0  = (const float*)d_in[4];
  const float* Wt0  = (const float*)d_in[5];
  const float* bt0  = (const float*)d_in[6];
  const float* tau0 = (const float*)d_in[7];
  const float* g0   = (const float*)d_in[8];
  const float* be0  = (const float*)d_in[9];
  const float* Wh1  = (const float*)d_in[10];
  const float* bh1  = (const float*)d_in[11];
  const float* Wx1  = (const float*)d_in[12];
  const float* bx1  = (const float*)d_in[13];
  const float* Wt1  = (const float*)d_in[14];
  const float* bt1  = (const float*)d_in[15];
  const float* tau1 = (const float*)d_in[16];
  const float* g1   = (const float*)d_in[17];
  const float* be1  = (const float*)d_in[18];
  float* out        = (float*)d_out;

  ltc_scan<<<B_, NT_, 0, stream>>>(x, Wh0, bh0, Wx0, bx0, Wt0, bt0, tau0, g0, be0,
                                   Wh1, bh1, Wx1, bx1, Wt1, bt1, tau1, g1, be1, out);
}

// Round 8
// 1313.952 us; speedup vs baseline: 1.2079x; 1.2079x over previous
//
#include <hip/hip_runtime.h>
#include <stdint.h>

// LTC encoder B=256,T=1024,F=64,H=128. One WG per batch row.
// Wave-specialized: waves 0-3 (A) = layer 0 step t, waves 4-7 (B) = layer 1 step t-1.
// R3/R4/R6 lesson: allocator caps ~112-128 VGPR regardless of attrs/pins; fp32
// weights (160-192/thread) can't be resident -> L2/scratch-bound.
// R8: weights packed f16 (2/VGPR) + v_dot2_f32_f16 (2 MAC/instr, fp32 acc):
// demand ~130 regs fits the cap; FMA issue floor halves; h/x broadcast as packed
// f16 through LDS; per-row `hold` state kept in registers.
// (R7 = same idea, killed by __fp16-vs-_Float16 vector type mismatch on cvt_pkrtz.)

#define B_ 256
#define T_ 1024
#define F_ 64
#define H_ 128
#define EPS_ 1e-5f
#define NT_ 512

typedef _Float16 h2 __attribute__((ext_vector_type(2)));
typedef __fp16  f16v2 __attribute__((ext_vector_type(2)));

__device__ __forceinline__ h2 pkf16(float a, float b) {
  union { f16v2 f; h2 h; } c;
  c.f = __builtin_amdgcn_cvt_pkrtz(a, b);
  return c.h;
}
__device__ __forceinline__ h2 as_h2(uint32_t u) { union { uint32_t u; h2 h; } c; c.u = u; return c.h; }
__device__ __forceinline__ uint32_t as_u32(h2 h) { union { h2 h; uint32_t u; } c; c.h = h; return c.u; }

#if __has_builtin(__builtin_amdgcn_fdot2)
__device__ __forceinline__ float fdot2(h2 a, h2 b, float c) { return __builtin_amdgcn_fdot2(a, b, c, false); }
#else
__device__ __forceinline__ float fdot2(h2 a, h2 b, float c) { return c + (float)a.x * (float)b.x + (float)a.y * (float)b.y; }
#endif

__device__ __forceinline__ float tanh_fast(float a) {
  float aa = fabsf(a);
  float e  = __expf(2.f * aa);
  float th = 1.f - 2.f / (e + 1.f);
  return copysignf(th, a);
}
__device__ __forceinline__ float softplus_fast(float x) {
  return (x > 20.f) ? x : __logf(1.f + __expf(x));
}

// 16 packed-f16 pairs (one K-quarter, 32 values) from LDS via 4x ds_read_b128
#define LOADHV(HV_, SRC_) { \
  const uint4* _p = (const uint4*)(SRC_); \
  uint4 _a = _p[0], _b = _p[1], _c = _p[2], _d = _p[3]; \
  HV_[0]=as_h2(_a.x); HV_[1]=as_h2(_a.y); HV_[2]=as_h2(_a.z); HV_[3]=as_h2(_a.w); \
  HV_[4]=as_h2(_b.x); HV_[5]=as_h2(_b.y); HV_[6]=as_h2(_b.z); HV_[7]=as_h2(_b.w); \
  HV_[8]=as_h2(_c.x); HV_[9]=as_h2(_c.y); HV_[10]=as_h2(_c.z); HV_[11]=as_h2(_c.w); \
  HV_[12]=as_h2(_d.x); HV_[13]=as_h2(_d.y); HV_[14]=as_h2(_d.z); HV_[15]=as_h2(_d.w); }

// quad combine (DPP), cell math, LN (wave butterfly + LDS partials), packed h write.
// Exactly 2 __syncthreads.
__device__ __forceinline__ float ln_tail(
    float pa0, float pt0, float pa1, float pt1, float hold,
    float bhx, float btr, float taub, float gr, float ber,
    int par, int l, int wid, float2* part, int pbase,
    uint32_t* dstp, int jp, bool we)
{
  pa0 += __shfl_xor(pa0, 1); pa0 += __shfl_xor(pa0, 2);
  pt0 += __shfl_xor(pt0, 1); pt0 += __shfl_xor(pt0, 2);
  pa1 += __shfl_xor(pa1, 1); pa1 += __shfl_xor(pa1, 2);
  pt1 += __shfl_xor(pt1, 1); pt1 += __shfl_xor(pt1, 2);
  float aa = par ? pa1 : pa0;       // parity split: one row per lane
  float tt = par ? pt1 : pt0;
  float f   = tanh_fast(aa + bhx);
  float tau = taub + softplus_fast(tt + btr);
  float hc  = fmaf(f - hold, __builtin_amdgcn_rcpf(tau), hold);
  float s = hc, s2 = hc * hc;
  #pragma unroll
  for (int off = 1; off <= 32; off <<= 1) {
    s  += __shfl_xor(s, off);
    s2 += __shfl_xor(s2, off);
  }
  if (l == 0) part[wid] = make_float2(s, s2);
  __syncthreads();                                   // barrier 1
  float4 p01 = *(const float4*)(part + pbase);
  float4 p23 = *(const float4*)(part + pbase + 2);
  float mu = (p01.x + p01.z + p23.x + p23.z) * (1.f / 256.f);  // each row counted 2x
  float m2 = (p01.y + p01.w + p23.y + p23.w) * (1.f / 256.f);
  float rstd = rsqrtf(m2 - mu * mu + EPS_);
  float hn = fmaf((hc - mu) * rstd, gr, ber);
  // pack rows (k, k+1): partner row's hn lives at lane l+4 (same q, par, k+1)
  float hn2 = __shfl_down(hn, 4);
  if (we && (l & 6) == 0) dstp[jp >> 1] = as_u32(pkf16(hn, hn2));
  __syncthreads();                                   // barrier 2
  return hn;
}

__global__ void __attribute__((amdgpu_flat_work_group_size(NT_, NT_)))
                __attribute__((amdgpu_waves_per_eu(2, 2)))
ltc_scan(
    const float* __restrict__ x,
    const float* __restrict__ Wh0, const float* __restrict__ bh0,
    const float* __restrict__ Wx0, const float* __restrict__ bx0,
    const float* __restrict__ Wt0, const float* __restrict__ bt0,
    const float* __restrict__ tau0, const float* __restrict__ g0,
    const float* __restrict__ be0,
    const float* __restrict__ Wh1, const float* __restrict__ bh1,
    const float* __restrict__ Wx1, const float* __restrict__ bx1,
    const float* __restrict__ Wt1, const float* __restrict__ bt1,
    const float* __restrict__ tau1, const float* __restrict__ g1,
    const float* __restrict__ be1,
    float* __restrict__ out)
{
  __shared__ __align__(16) uint32_t h0p[2][64];   // h0 as packed f16 pairs, dbuf
  __shared__ __align__(16) uint32_t h1p[64];      // h1 packed
  __shared__ __align__(16) float2 part[8];

  const int tid = threadIdx.x;
  const int wid = tid >> 6;
  const int l   = tid & 63;
  const int gw  = wid & 3;         // wave within group
  const int q   = l & 3;           // K-quarter
  const int k   = l >> 2;          // 0..15
  const int par = l & 1;
  const int j0  = gw * 16 + k;     // rows j0 and j0+64
  const int jp  = j0 + (par ? 64 : 0);
  const int b   = blockIdx.x;

  if (tid < 64) { h0p[0][tid] = 0u; h0p[1][tid] = 0u; h1p[tid] = 0u; }
  __syncthreads();

  if (wid < 4) {
    // ================= group A: layer 0, step t = i =================
    h2 awh[32], awx[16], awt[16];
    {
      const float4* p0 = (const float4*)(Wh0 + j0 * H_ + q * 32);
      const float4* p1 = (const float4*)(Wh0 + (j0 + 64) * H_ + q * 32);
      #pragma unroll
      for (int i2 = 0; i2 < 8; ++i2) {
        float4 v = p0[i2]; awh[2*i2] = pkf16(v.x, v.y); awh[2*i2+1] = pkf16(v.z, v.w);
        float4 w = p1[i2]; awh[16+2*i2] = pkf16(w.x, w.y); awh[16+2*i2+1] = pkf16(w.z, w.w);
      }
      const float4* q0 = (const float4*)(Wx0 + j0 * F_ + q * 16);
      const float4* q1 = (const float4*)(Wx0 + (j0 + 64) * F_ + q * 16);
      #pragma unroll
      for (int i2 = 0; i2 < 4; ++i2) {
        float4 v = q0[i2]; awx[2*i2] = pkf16(v.x, v.y); awx[2*i2+1] = pkf16(v.z, v.w);
        float4 w = q1[i2]; awx[8+2*i2] = pkf16(w.x, w.y); awx[8+2*i2+1] = pkf16(w.z, w.w);
      }
      const float4* r0 = (const float4*)(Wt0 + j0 * F_ + q * 16);
      const float4* r1 = (const float4*)(Wt0 + (j0 + 64) * F_ + q * 16);
      #pragma unroll
      for (int i2 = 0; i2 < 4; ++i2) {
        float4 v = r0[i2]; awt[2*i2] = pkf16(v.x, v.y); awt[2*i2+1] = pkf16(v.z, v.w);
        float4 w = r1[i2]; awt[8+2*i2] = pkf16(w.x, w.y); awt[8+2*i2+1] = pkf16(w.z, w.w);
      }
    }
    const float bhx = bh0[jp] + bx0[jp];
    const float btr = bt0[jp];
    const float taub = tau0[jp];
    const float gr = g0[jp], ber = be0[jp];

    const float4* xg = (const float4*)(x + (size_t)b * (T_ * F_));
    // distance-2 register prefetch of the thread's x quarter (16 fp32)
    float4 xa0 = xg[q * 4 + 0], xa1 = xg[q * 4 + 1], xa2 = xg[q * 4 + 2], xa3 = xg[q * 4 + 3];
    float4 xb0 = xg[16 + q * 4 + 0], xb1 = xg[16 + q * 4 + 1],
           xb2 = xg[16 + q * 4 + 2], xb3 = xg[16 + q * 4 + 3];

    float hprevA = 0.f;
    auto stepA = [&](int i, float4& x0, float4& x1, float4& x2, float4& x3) {
      h2 hv[16];
      LOADHV(hv, h0p[i & 1] + q * 16)
      h2 xv[8];
      xv[0] = pkf16(x0.x, x0.y); xv[1] = pkf16(x0.z, x0.w);
      xv[2] = pkf16(x1.x, x1.y); xv[3] = pkf16(x1.z, x1.w);
      xv[4] = pkf16(x2.x, x2.y); xv[5] = pkf16(x2.z, x2.w);
      xv[6] = pkf16(x3.x, x3.y); xv[7] = pkf16(x3.z, x3.w);
      float pa0 = 0.f, pa1 = 0.f, pt0 = 0.f, pt1 = 0.f;
      #pragma unroll
      for (int ii = 0; ii < 16; ++ii) {
        pa0 = fdot2(awh[ii], hv[ii], pa0);
        pa1 = fdot2(awh[16 + ii], hv[ii], pa1);
      }
      #pragma unroll
      for (int ii = 0; ii < 8; ++ii) {
        pa0 = fdot2(awx[ii], xv[ii], pa0);  pa1 = fdot2(awx[8 + ii], xv[ii], pa1);
        pt0 = fdot2(awt[ii], xv[ii], pt0);  pt1 = fdot2(awt[8 + ii], xv[ii], pt1);
      }
      int tn = i + 2; if (tn > T_ - 1) tn = T_ - 1;   // reload this buffer for t=i+2
      const float4* xp = xg + tn * 16 + q * 4;
      x0 = xp[0]; x1 = xp[1]; x2 = xp[2]; x3 = xp[3];
      float hn = ln_tail(pa0, pt0, pa1, pt1, hprevA, bhx, btr, taub, gr, ber,
                         par, l, wid, part, 0, h0p[(i + 1) & 1], jp, true);
      hprevA = hn;
    };

    for (int i = 0; i < T_; i += 2) {
      stepA(i, xa0, xa1, xa2, xa3);
      stepA(i + 1, xb0, xb1, xb2, xb3);
    }
    stepA(T_, xa0, xa1, xa2, xa3);                   // pipeline drain (result unused)
  } else {
    // ================= group B: layer 1, step t = i-1 =================
    h2 swh[32], swx[32], swt[32];
    {
      const float4* p0 = (const float4*)(Wh1 + j0 * H_ + q * 32);
      const float4* p1 = (const float4*)(Wh1 + (j0 + 64) * H_ + q * 32);
      #pragma unroll
      for (int i2 = 0; i2 < 8; ++i2) {
        float4 v = p0[i2]; swh[2*i2] = pkf16(v.x, v.y); swh[2*i2+1] = pkf16(v.z, v.w);
        float4 w = p1[i2]; swh[16+2*i2] = pkf16(w.x, w.y); swh[16+2*i2+1] = pkf16(w.z, w.w);
      }
      const float4* q0 = (const float4*)(Wx1 + j0 * H_ + q * 32);
      const float4* q1 = (const float4*)(Wx1 + (j0 + 64) * H_ + q * 32);
      #pragma unroll
      for (int i2 = 0; i2 < 8; ++i2) {
        float4 v = q0[i2]; swx[2*i2] = pkf16(v.x, v.y); swx[2*i2+1] = pkf16(v.z, v.w);
        float4 w = q1[i2]; swx[16+2*i2] = pkf16(w.x, w.y); swx[16+2*i2+1] = pkf16(w.z, w.w);
      }
      const float4* r0 = (const float4*)(Wt1 + j0 * H_ + q * 32);
      const float4* r1 = (const float4*)(Wt1 + (j0 + 64) * H_ + q * 32);
      #pragma unroll
      for (int i2 = 0; i2 < 8; ++i2) {
        float4 v = r0[i2]; swt[2*i2] = pkf16(v.x, v.y); swt[2*i2+1] = pkf16(v.z, v.w);
        float4 w = r1[i2]; swt[16+2*i2] = pkf16(w.x, w.y); swt[16+2*i2+1] = pkf16(w.z, w.w);
      }
    }
    const float bhx = bh1[jp] + bx1[jp];
    const float btr = bt1[jp];
    const float taub = tau1[jp];
    const float gr = g1[jp], ber = be1[jp];

    float hprevB = 0.f, hnlast = 0.f;
    for (int i = 0; i <= T_; ++i) {
      h2 hv[16];
      LOADHV(hv, h1p + q * 16)                       // h1[i-2]
      float pa0 = 0.f, pa1 = 0.f, pt0 = 0.f, pt1 = 0.f;
      #pragma unroll
      for (int ii = 0; ii < 16; ++ii) {
        pa0 = fdot2(swh[ii], hv[ii], pa0);
        pa1 = fdot2(swh[16 + ii], hv[ii], pa1);
      }
      LOADHV(hv, h0p[i & 1] + q * 16)                // h0[i-1]
      #pragma unroll
      for (int ii = 0; ii < 16; ++ii) {
        pa0 = fdot2(swx[ii], hv[ii], pa0);  pa1 = fdot2(swx[16 + ii], hv[ii], pa1);
        pt0 = fdot2(swt[ii], hv[ii], pt0);  pt1 = fdot2(swt[16 + ii], hv[ii], pt1);
      }
      float hn = ln_tail(pa0, pt0, pa1, pt1, hprevB, bhx, btr, taub, gr, ber,
                         par, l, wid, part, 4, h1p, jp, i > 0);
      if (i > 0) { hprevB = hn; hnlast = hn; }
    }
    if ((l & 2) == 0) out[b * H_ + jp] = hnlast;     // h1[T-1]
  }
}

extern "C" void kernel_launch(void* const* d_in, const int* in_sizes, int n_in,
                              void* d_out, int out_size, void* d_ws, size_t ws_size,
                              hipStream_t stream) {
  const float* x    = (const float*)d_in[0];
  const float* Wh0  = (const float*)d_in[1];
  const float* bh0  = (const float*)d_in[2];
  const float* Wx0  = (const float*)d_in[3];
  const float* bx0  = (const float*)d_in[4];
  const float* Wt0  = (const float*)d_in[5];
  const float* bt0  = (const float*)d_in[6];
  const float* tau0 = (const float*)d_in[7];
  const float* g0   = (const float*)d_in[8];
  const float* be0  = (const float*)d_in[9];
  const float* Wh1  = (const float*)d_in[10];
  const float* bh1  = (const float*)d_in[11];
  const float* Wx1  = (const float*)d_in[12];
  const float* bx1  = (const float*)d_in[13];
  const float* Wt1  = (const float*)d_in[14];
  const float* bt1  = (const float*)d_in[15];
  const float* tau1 = (const float*)d_in[16];
  const float* g1   = (const float*)d_in[17];
  const float* be1  = (const float*)d_in[18];
  float* out        = (float*)d_out;

  ltc_scan<<<B_, NT_, 0, stream>>>(x, Wh0, bh0, Wx0, bx0, Wt0, bt0, tau0, g0, be0,
                                   Wh1, bh1, Wx1, bx1, Wt1, bt1, tau1, g1, be1, out);
}